// Round 25
// baseline (190.767 us; speedup 1.0000x reference)
//
#include <hip/hip_runtime.h>
#include <stdint.h>

typedef __attribute__((ext_vector_type(8))) short short8;
typedef __attribute__((ext_vector_type(4))) float f32x4;
typedef __attribute__((ext_vector_type(16))) float f32x16;
typedef __attribute__((ext_vector_type(4))) unsigned int u32x4;
typedef __attribute__((ext_vector_type(2))) unsigned int u32x2;

#define AS1 __attribute__((address_space(1)))
#define AS3 __attribute__((address_space(3)))

// XOR swizzle (16B-chunk granularity) for 64-short rows.
#define FSWZ(row) ((((row)) & 7) ^ (((row) >> 3) & 7))

// 0.125 * log2(e): folded into K at GEMM epilogue; softmax in log2 domain.
#define KSCL 0.18033688f

__device__ __forceinline__ void gload_lds16(const void* g, void* l) {
  __builtin_amdgcn_global_load_lds((const AS1 void*)g, (AS3 void*)l, 16, 0, 0);
}

__device__ __forceinline__ short f2bf(float f) {
  uint32_t u = __float_as_uint(f);
  u += 0x7fffu + ((u >> 16) & 1u);
  return (short)(u >> 16);
}

__device__ __forceinline__ unsigned int cvtpk(float lo, float hi) {
  unsigned int r;
  asm("v_cvt_pk_bf16_f32 %0, %1, %2" : "=v"(r) : "v"(lo), "v"(hi));
  return r;
}

__device__ __forceinline__ float max3f(float a, float b, float c) {
  return fmaxf(fmaxf(a, b), c);  // fuses to v_max3_f32
}

// ---------------- fused fp32 -> bf16 conversion (x, w_qkv, w_out) ---------
__global__ __launch_bounds__(256) void cvt_all(const float* __restrict__ x,
                                               const float* __restrict__ wq,
                                               const float* __restrict__ wo,
                                               short* __restrict__ xb,
                                               short* __restrict__ wqb,
                                               short* __restrict__ wob) {
  int i = blockIdx.x * 256 + threadIdx.x;
  const float* in;
  short* out;
  if (i < 1048576) {
    in = x + (size_t)i * 8;
    out = xb + (size_t)i * 8;
  } else if (i < 1441792) {
    int j = i - 1048576;
    in = wq + (size_t)j * 8;
    out = wqb + (size_t)j * 8;
  } else {
    int j = i - 1441792;
    in = wo + (size_t)j * 8;
    out = wob + (size_t)j * 8;
  }
  const float4* p = (const float4*)in;
  float4 a = p[0], b = p[1];
  short8 o;
  o[0] = f2bf(a.x); o[1] = f2bf(a.y); o[2] = f2bf(a.z); o[3] = f2bf(a.w);
  o[4] = f2bf(b.x); o[5] = f2bf(b.y); o[6] = f2bf(b.z); o[7] = f2bf(b.w);
  *(short8*)out = o;
}

// ---------------- GEMM: C[M,N] = A[M,K] * B[N,K]^T ----------------
// T3-minimum pipeline: double-buffered LDS, ONE barrier per K-step.
// epi==0: Q/K blocks stage C through LDS -> coalesced short8 stores;
// V blocks (bn>=2048) transpose through LDS -> vT [bh][dh][s].
__global__ __launch_bounds__(256) void gemm_bt(const short* __restrict__ A,
                                               const short* __restrict__ B,
                                               int K, int epi,
                                               short* __restrict__ q,
                                               short* __restrict__ k,
                                               short* __restrict__ v,
                                               float* __restrict__ outF, int N) {
  __shared__ short Sm[32768];  // 2 x (A 8192 + B 8192); epilogue reuses flat
  const int tid = threadIdx.x;
  const int lane = tid & 63;
  const int wv = tid >> 6;
  const int wr = wv >> 1, wc = wv & 1;
  // XCD swizzle: nwg % 8 == 0 for both our launches (1536, 512)
  const int gx = gridDim.x;
  const int lin = blockIdx.y * gx + blockIdx.x;
  const int cpx = (gx * gridDim.y) >> 3;
  const int swz = (lin & 7) * cpx + (lin >> 3);
  const int bm = (swz / gx) * 128, bn = (swz % gx) * 128;
  const int l15 = lane & 15, l4 = lane >> 4;

  f32x4 acc[4][4] = {};
  const int NIT = K >> 6;  // 16 K-steps

  // prologue: stage K-step 0 into buf 0
#pragma unroll
  for (int i = 0; i < 4; ++i) {
    int c = i * 256 + tid;
    int row = c >> 3, col = (c & 7) * 8;
    gload_lds16(A + (size_t)(bm + row) * K + col, (char*)(Sm) + (size_t)c * 16);
    gload_lds16(B + (size_t)(bn + row) * K + col, (char*)(Sm + 8192) + (size_t)c * 16);
  }

  for (int it = 0; it < NIT; ++it) {
    const int cur = it & 1;
    const short* Al = Sm + cur * 16384;
    const short* Bl = Al + 8192;
    __syncthreads();  // buf[cur] DMAs drained; buf[cur^1] readers retired

    if (it + 1 < NIT) {  // issue next K-step's DMAs; fly over compute
      const int kt = (it + 1) << 6;
      short* An = Sm + (cur ^ 1) * 16384;
      short* Bn = An + 8192;
#pragma unroll
      for (int i = 0; i < 4; ++i) {
        int c = i * 256 + tid;
        int row = c >> 3, col = (c & 7) * 8;
        gload_lds16(A + (size_t)(bm + row) * K + kt + col, (char*)An + (size_t)c * 16);
        gload_lds16(B + (size_t)(bn + row) * K + kt + col, (char*)Bn + (size_t)c * 16);
      }
    }

#pragma unroll
    for (int ks = 0; ks < 2; ++ks) {
      short8 af[4], bf[4];
#pragma unroll
      for (int mf = 0; mf < 4; ++mf)
        af[mf] = *(const short8*)&Al[(wr * 64 + mf * 16 + l15) * 64 + ks * 32 + l4 * 8];
#pragma unroll
      for (int nf = 0; nf < 4; ++nf)
        bf[nf] = *(const short8*)&Bl[(wc * 64 + nf * 16 + l15) * 64 + ks * 32 + l4 * 8];
#pragma unroll
      for (int mf = 0; mf < 4; ++mf)
#pragma unroll
        for (int nf = 0; nf < 4; ++nf)
          acc[mf][nf] =
              __builtin_amdgcn_mfma_f32_16x16x32_bf16(af[mf], bf[nf], acc[mf][nf], 0, 0, 0);
    }
  }
  __syncthreads();  // all compute done before epilogue reuses Sm

  if (epi == 0) {
    if (bn >= 2048) {
      // ---- V block: transpose C-tile through LDS, coalesced store ----
#pragma unroll
      for (int mf = 0; mf < 4; ++mf)
#pragma unroll
        for (int r = 0; r < 4; ++r) {
          int srow = wr * 64 + mf * 16 + l4 * 4 + r;
#pragma unroll
          for (int nf = 0; nf < 4; ++nf) {
            int dloc = wc * 64 + nf * 16 + l15;
            Sm[dloc * 132 + srow] = f2bf(acc[mf][nf][r]);
          }
        }
      __syncthreads();
      const int bb = bm >> 11, s0 = bm & 2047;
      const int dbase = bn - 2048;
#pragma unroll
      for (int it = 0; it < 8; ++it) {
        int row = it * 16 + (tid >> 4);   // dloc 0..127
        int scol = (tid & 15) * 8;        // srow chunk
        short8 val = *(const short8*)&Sm[row * 132 + scol];
        int dglob = dbase + row;
        int hh = dglob >> 6, dh = dglob & 63;
        *(short8*)&v[((size_t)(bb * 16 + hh) * 64 + dh) * 2048 + s0 + scol] = val;
      }
    } else {
      // ---- Q/K block: stage [srow][dloc] in LDS, coalesced short8 store ----
      const bool isK = (bn >= 1024);
      const float scl = isK ? KSCL : 1.0f;
#pragma unroll
      for (int mf = 0; mf < 4; ++mf)
#pragma unroll
        for (int r = 0; r < 4; ++r) {
          int srow = wr * 64 + mf * 16 + l4 * 4 + r;
#pragma unroll
          for (int nf = 0; nf < 4; ++nf) {
            int dloc = wc * 64 + nf * 16 + l15;
            Sm[srow * 132 + dloc] = f2bf(acc[mf][nf][r] * scl);
          }
        }
      __syncthreads();
      const int bb = bm >> 11, s0 = bm & 2047;
      short* dst = isK ? k : q;
#pragma unroll
      for (int it = 0; it < 8; ++it) {
        int row = it * 16 + (tid >> 4);   // srow (s offset) 0..127
        int nc8 = (tid & 15) * 8;         // dloc chunk
        short8 val = *(const short8*)&Sm[row * 132 + nc8];
        int n = bn + nc8;                  // bn%64==0 -> dh chunk-aligned
        int h = (n >> 6) & 15, dh = n & 63;
        *(short8*)&dst[((size_t)(bb * 16 + h) * 2048 + s0 + row) * 64 + dh] = val;
      }
    }
  } else {
#pragma unroll
    for (int mf = 0; mf < 4; ++mf)
#pragma unroll
      for (int r = 0; r < 4; ++r) {
        int m = bm + wr * 64 + mf * 16 + l4 * 4 + r;
#pragma unroll
        for (int nf = 0; nf < 4; ++nf) {
          int n = bn + wc * 64 + nf * 16 + l15;
          outF[(size_t)m * N + n] = acc[mf][nf][r];
        }
      }
  }
}

// ---------------- causal flash attention (R24 + MFMA-ones l-sum) ----------
// Q,K: [BH=64][S=2048][64] bf16 (K pre-scaled). V: [BH=64][64][S=2048] bf16.
// Out: [B][S][H][64] bf16.
// Softmax denominator on the MFMA pipe (oacc3 += 1^T x P^T): kernel is now
// VALU-issue-bound (64% busy) with MFMA 84% idle, so trading the ~33-op
// VALU sum tree for 4 MFMA issues should pay (retest of R20 in new regime).
__global__ __launch_bounds__(256) void attn_fwd(const short* __restrict__ Qb,
                                                const short* __restrict__ Kb,
                                                const short* __restrict__ Vtg,
                                                short* __restrict__ Ob) {
  __shared__ short Kl[2][64 * 64];  // [k][d], FSWZ via pre-swizzled src
  __shared__ short Vt[2][64 * 64];  // [d][k], FSWZ via pre-swizzled src
  const int tid = threadIdx.x, lane = tid & 63, wv = tid >> 6;
  const int l31 = lane & 31, l32 = lane >> 5;
  const int bh = blockIdx.x;
  const int qt = (int)gridDim.y - 1 - (int)blockIdx.y;  // heavy-first
  const int b = bh >> 4, h = bh & 15;
  const size_t base = (size_t)bh * 2048 * 64;   // Q/K base ([s][d])
  const size_t baseV = (size_t)bh * 64 * 2048;  // V^T base ([d][s])
  const int q0 = qt * 128;
  const int qw0 = q0 + wv * 32;
  const int qg = qw0 + l31;

  // Q as B-fragments: qf[dk] covers d = dk*16 + l32*8 + e
  short8 qf[4];
#pragma unroll
  for (int dk = 0; dk < 4; ++dk)
    qf[dk] = *(const short8*)(Qb + base + (size_t)qg * 64 + dk * 16 + l32 * 8);

  // ones A-fragment (bf16 1.0 = 0x3F80) for the l-sum MFMA
  short8 ones;
#pragma unroll
  for (int j = 0; j < 8; ++j) ones[j] = (short)0x3F80;

  f32x16 oacc[2] = {};
  f32x16 oacc3 = {};  // column-sums of P (denominator); element 0 used
  float mrun = -1e30f;

  const int nt = 2 * qt + 2;
  // prologue: issue tile 0 DMAs (K rows = k, V^T rows = d; both swizzled src)
#pragma unroll
  for (int i = 0; i < 2; ++i) {
    int c = i * 256 + tid;
    int row = c >> 3, j = c & 7;
    int js = (j ^ FSWZ(row)) * 8;
    gload_lds16(Kb + base + (size_t)row * 64 + js, (char*)Kl[0] + (size_t)c * 16);
    gload_lds16(Vtg + baseV + (size_t)row * 2048 + js, (char*)Vt[0] + (size_t)c * 16);
  }

  for (int t = 0; t < nt; ++t) {
    const int cur = t & 1;
    const int kv0 = t * 64;
    __syncthreads();  // buf[cur] DMAs drained; buf[cur^1] readers retired

    if (t + 1 < nt) {  // issue next tile's DMAs; fly over compute
      const int kv1 = kv0 + 64;
#pragma unroll
      for (int i = 0; i < 2; ++i) {
        int c = i * 256 + tid;
        int row = c >> 3, j = c & 7;
        int js = (j ^ FSWZ(row)) * 8;
        gload_lds16(Kb + base + (size_t)(kv1 + row) * 64 + js,
                    (char*)Kl[cur ^ 1] + (size_t)c * 16);
        gload_lds16(Vtg + baseV + (size_t)row * 2048 + kv1 + js,
                    (char*)Vt[cur ^ 1] + (size_t)c * 16);
      }
    }

    if (kv0 <= qw0 + 31) {
      // ---- QK^T (swapped): sc[kb] = S^T tile ----
      f32x16 sc[2] = {};
#pragma unroll
      for (int dk = 0; dk < 4; ++dk)
#pragma unroll
        for (int kb = 0; kb < 2; ++kb) {
          int row = kb * 32 + l31;
          short8 kf =
              *(const short8*)&Kl[cur][row * 64 + (((dk * 2 + l32) ^ FSWZ(row)) * 8)];
          sc[kb] = __builtin_amdgcn_mfma_f32_32x32x16_bf16(kf, qf[dk], sc[kb], 0, 0, 0);
        }

      // ---- causal mask: only on frontier tiles (wave-uniform branch) ----
      if (kv0 + 63 > qw0) {
        const int thr2 = qg - kv0 - 4 * l32;
#pragma unroll
        for (int kb = 0; kb < 2; ++kb)
#pragma unroll
          for (int r = 0; r < 16; ++r) {
            if (kb * 32 + ((r & 3) + 8 * (r >> 2)) > thr2) sc[kb][r] = -1e30f;
          }
      }

      // ---- softmax (K pre-scaled; log2 domain); lane owns q-row l31 ----
      float m0 = max3f(sc[0][0], sc[0][1], sc[0][2]);
      float m1 = max3f(sc[0][3], sc[0][4], sc[0][5]);
      float m2 = max3f(sc[0][6], sc[0][7], sc[0][8]);
      float m3 = max3f(sc[0][9], sc[0][10], sc[0][11]);
      float m4 = max3f(sc[0][12], sc[0][13], sc[0][14]);
      float m5 = max3f(sc[0][15], sc[1][0], sc[1][1]);
      float m6 = max3f(sc[1][2], sc[1][3], sc[1][4]);
      float m7 = max3f(sc[1][5], sc[1][6], sc[1][7]);
      float m8 = max3f(sc[1][8], sc[1][9], sc[1][10]);
      float m9 = max3f(sc[1][11], sc[1][12], sc[1][13]);
      float ma = fmaxf(sc[1][14], sc[1][15]);
      float mb = max3f(m0, m1, m2);
      float mc = max3f(m3, m4, m5);
      float md = max3f(m6, m7, m8);
      float me = max3f(m9, ma, mb);
      float mx = max3f(mc, md, me);
      {  // lane^32 exchange via permlane (partner = l32 ? ret.x : ret.y)
        u32x2 mm = __builtin_amdgcn_permlane32_swap(__float_as_uint(mx),
                                                    __float_as_uint(mx), false, false);
        mx = fmaxf(mx, __uint_as_float(l32 ? mm[0] : mm[1]));
      }
      // defer-max: rescale only when max grew past THR (=8*log2e)
      if (!__all(mx - mrun <= 11.5416f)) {
        float mnew = fmaxf(mrun, mx);
        float alpha = exp2f(mrun - mnew);
        oacc3[0] *= alpha;
#pragma unroll
        for (int dt = 0; dt < 2; ++dt)
#pragma unroll
          for (int r = 0; r < 16; ++r) oacc[dt][r] *= alpha;
        mrun = mnew;
      }
      float pp[2][16];
#pragma unroll
      for (int kb = 0; kb < 2; ++kb)
#pragma unroll
        for (int r = 0; r < 16; ++r) pp[kb][r] = exp2f(sc[kb][r] - mrun);

      // ---- pack P pairs: W[kb][g][u] covers k0 = kb*32+8g+4*l32+2u ----
      unsigned int W[2][4][2];
#pragma unroll
      for (int kb = 0; kb < 2; ++kb)
#pragma unroll
        for (int g = 0; g < 4; ++g)
#pragma unroll
          for (int u = 0; u < 2; ++u)
            W[kb][g][u] = cvtpk(pp[kb][g * 4 + 2 * u], pp[kb][g * 4 + 2 * u + 1]);

      // ---- redistribute into PV B-fragments via permlane32_swap ----
      u32x4 pf[4];
#pragma unroll
      for (int kblk = 0; kblk < 4; ++kblk) {
        const int kbh = kblk >> 1;
#pragma unroll
        for (int u = 0; u < 2; ++u) {
          u32x2 rr = __builtin_amdgcn_permlane32_swap(
              W[kbh][2 * (kblk & 1)][u], W[kbh][2 * (kblk & 1) + 1][u], false, false);
          pf[kblk][0 + u] = rr[0];
          pf[kblk][2 + u] = rr[1];
        }
      }

      // ---- PV (swapped): oacc[dt] += V^T[dt] x P^T; oacc3 += 1 x P^T ----
#pragma unroll
      for (int dt = 0; dt < 2; ++dt)
#pragma unroll
        for (int kblk = 0; kblk < 4; ++kblk) {
          int row = dt * 32 + l31;
          short8 vf =
              *(const short8*)&Vt[cur][row * 64 + (((kblk * 2 + l32) ^ FSWZ(row)) * 8)];
          oacc[dt] = __builtin_amdgcn_mfma_f32_32x32x16_bf16(
              vf, __builtin_bit_cast(short8, pf[kblk]), oacc[dt], 0, 0, 0);
        }
#pragma unroll
      for (int kblk = 0; kblk < 4; ++kblk)
        oacc3 = __builtin_amdgcn_mfma_f32_32x32x16_bf16(
            ones, __builtin_bit_cast(short8, pf[kblk]), oacc3, 0, 0, 0);
    }
  }

  // ---- epilogue: denominator = oacc3[0]; pack adjacent-d dword stores ----
  float inv = 1.f / oacc3[0];
#pragma unroll
  for (int dt = 0; dt < 2; ++dt)
#pragma unroll
    for (int r = 0; r < 16; r += 2) {
      int d = dt * 32 + (r & 3) + 8 * (r >> 2) + 4 * l32;  // r even -> d even
      unsigned int pk = cvtpk(oacc[dt][r] * inv, oacc[dt][r + 1] * inv);
      *(unsigned int*)&Ob[(size_t)(b * 2048 + qg) * 1024 + h * 64 + d] = pk;
    }
}

// ---------------- launch ----------------
extern "C" void kernel_launch(void* const* d_in, const int* in_sizes, int n_in,
                              void* d_out, int out_size, void* d_ws, size_t ws_size,
                              hipStream_t stream) {
  const float* x = (const float*)d_in[0];      // [4,2048,1024]
  const float* w_qkv = (const float*)d_in[1];  // [3072,1024]
  const float* w_out = (const float*)d_in[2];  // [1024,1024]
  float* out = (float*)d_out;                  // [4,2048,1024] fp32

  char* ws = (char*)d_ws;
  const size_t MB = 1024 * 1024;
  short* xb    = (short*)(ws + 0 * MB);    // 16 MB; dead after QKV GEMM
  short* wqkvb = (short*)(ws + 16 * MB);   // 6 MB
  short* woutb = (short*)(ws + 22 * MB);   // 2 MB
  short* qb    = (short*)(ws + 24 * MB);   // 16 MB  [64][2048][64]
  short* kb    = (short*)(ws + 40 * MB);   // 16 MB (pre-scaled by KSCL)
  short* vb    = (short*)(ws + 56 * MB);   // 16 MB  [64][64][2048] (V^T)
  short* ao    = xb;                       // reuse xb for attn output

  cvt_all<<<6144, 256, 0, stream>>>(x, w_qkv, w_out, xb, wqkvb, woutb);

  gemm_bt<<<dim3(3072 / 128, 8192 / 128), 256, 0, stream>>>(
      xb, wqkvb, 1024, 0, qb, kb, vb, nullptr, 3072);

  attn_fwd<<<dim3(64, 16), 256, 0, stream>>>(qb, kb, vb, ao);

  gemm_bt<<<dim3(1024 / 128, 8192 / 128), 256, 0, stream>>>(
      ao, woutb, 1024, 1, nullptr, nullptr, nullptr, out, 1024);
}

// Round 26
// 183.597 us; speedup vs baseline: 1.0391x; 1.0391x over previous
//
#include <hip/hip_runtime.h>
#include <stdint.h>

typedef __attribute__((ext_vector_type(8))) short short8;
typedef __attribute__((ext_vector_type(4))) float f32x4;
typedef __attribute__((ext_vector_type(16))) float f32x16;
typedef __attribute__((ext_vector_type(4))) unsigned int u32x4;
typedef __attribute__((ext_vector_type(2))) unsigned int u32x2;

#define AS1 __attribute__((address_space(1)))
#define AS3 __attribute__((address_space(3)))

// XOR swizzle (16B-chunk granularity) for 64-short rows.
#define FSWZ(row) ((((row)) & 7) ^ (((row) >> 3) & 7))

// 0.125 * log2(e): folded into K at GEMM epilogue; softmax in log2 domain.
#define KSCL 0.18033688f

__device__ __forceinline__ void gload_lds16(const void* g, void* l) {
  __builtin_amdgcn_global_load_lds((const AS1 void*)g, (AS3 void*)l, 16, 0, 0);
}

__device__ __forceinline__ short f2bf(float f) {
  uint32_t u = __float_as_uint(f);
  u += 0x7fffu + ((u >> 16) & 1u);
  return (short)(u >> 16);
}

__device__ __forceinline__ unsigned int cvtpk(float lo, float hi) {
  unsigned int r;
  asm("v_cvt_pk_bf16_f32 %0, %1, %2" : "=v"(r) : "v"(lo), "v"(hi));
  return r;
}

__device__ __forceinline__ float max3f(float a, float b, float c) {
  return fmaxf(fmaxf(a, b), c);  // fuses to v_max3_f32
}

// ---------------- fused fp32 -> bf16 conversion (x, w_qkv, w_out) ---------
__global__ __launch_bounds__(256) void cvt_all(const float* __restrict__ x,
                                               const float* __restrict__ wq,
                                               const float* __restrict__ wo,
                                               short* __restrict__ xb,
                                               short* __restrict__ wqb,
                                               short* __restrict__ wob) {
  int i = blockIdx.x * 256 + threadIdx.x;
  const float* in;
  short* out;
  if (i < 1048576) {
    in = x + (size_t)i * 8;
    out = xb + (size_t)i * 8;
  } else if (i < 1441792) {
    int j = i - 1048576;
    in = wq + (size_t)j * 8;
    out = wqb + (size_t)j * 8;
  } else {
    int j = i - 1441792;
    in = wo + (size_t)j * 8;
    out = wob + (size_t)j * 8;
  }
  const float4* p = (const float4*)in;
  float4 a = p[0], b = p[1];
  short8 o;
  o[0] = f2bf(a.x); o[1] = f2bf(a.y); o[2] = f2bf(a.z); o[3] = f2bf(a.w);
  o[4] = f2bf(b.x); o[5] = f2bf(b.y); o[6] = f2bf(b.z); o[7] = f2bf(b.w);
  *(short8*)out = o;
}

// ---------------- GEMM: C[M,N] = A[M,K] * B[N,K]^T ----------------
// T3-minimum pipeline: double-buffered LDS, ONE barrier per K-step.
// epi==0: Q/K blocks stage C through LDS -> coalesced short8 stores;
// V blocks (bn>=2048) transpose through LDS -> vT [bh][dh][s].
__global__ __launch_bounds__(256) void gemm_bt(const short* __restrict__ A,
                                               const short* __restrict__ B,
                                               int K, int epi,
                                               short* __restrict__ q,
                                               short* __restrict__ k,
                                               short* __restrict__ v,
                                               float* __restrict__ outF, int N) {
  __shared__ short Sm[32768];  // 2 x (A 8192 + B 8192); epilogue reuses flat
  const int tid = threadIdx.x;
  const int lane = tid & 63;
  const int wv = tid >> 6;
  const int wr = wv >> 1, wc = wv & 1;
  // XCD swizzle: nwg % 8 == 0 for both our launches (1536, 512)
  const int gx = gridDim.x;
  const int lin = blockIdx.y * gx + blockIdx.x;
  const int cpx = (gx * gridDim.y) >> 3;
  const int swz = (lin & 7) * cpx + (lin >> 3);
  const int bm = (swz / gx) * 128, bn = (swz % gx) * 128;
  const int l15 = lane & 15, l4 = lane >> 4;

  f32x4 acc[4][4] = {};
  const int NIT = K >> 6;  // 16 K-steps

  // prologue: stage K-step 0 into buf 0
#pragma unroll
  for (int i = 0; i < 4; ++i) {
    int c = i * 256 + tid;
    int row = c >> 3, col = (c & 7) * 8;
    gload_lds16(A + (size_t)(bm + row) * K + col, (char*)(Sm) + (size_t)c * 16);
    gload_lds16(B + (size_t)(bn + row) * K + col, (char*)(Sm + 8192) + (size_t)c * 16);
  }

  for (int it = 0; it < NIT; ++it) {
    const int cur = it & 1;
    const short* Al = Sm + cur * 16384;
    const short* Bl = Al + 8192;
    __syncthreads();  // buf[cur] DMAs drained; buf[cur^1] readers retired

    if (it + 1 < NIT) {  // issue next K-step's DMAs; fly over compute
      const int kt = (it + 1) << 6;
      short* An = Sm + (cur ^ 1) * 16384;
      short* Bn = An + 8192;
#pragma unroll
      for (int i = 0; i < 4; ++i) {
        int c = i * 256 + tid;
        int row = c >> 3, col = (c & 7) * 8;
        gload_lds16(A + (size_t)(bm + row) * K + kt + col, (char*)An + (size_t)c * 16);
        gload_lds16(B + (size_t)(bn + row) * K + kt + col, (char*)Bn + (size_t)c * 16);
      }
    }

#pragma unroll
    for (int ks = 0; ks < 2; ++ks) {
      short8 af[4], bf[4];
#pragma unroll
      for (int mf = 0; mf < 4; ++mf)
        af[mf] = *(const short8*)&Al[(wr * 64 + mf * 16 + l15) * 64 + ks * 32 + l4 * 8];
#pragma unroll
      for (int nf = 0; nf < 4; ++nf)
        bf[nf] = *(const short8*)&Bl[(wc * 64 + nf * 16 + l15) * 64 + ks * 32 + l4 * 8];
#pragma unroll
      for (int mf = 0; mf < 4; ++mf)
#pragma unroll
        for (int nf = 0; nf < 4; ++nf)
          acc[mf][nf] =
              __builtin_amdgcn_mfma_f32_16x16x32_bf16(af[mf], bf[nf], acc[mf][nf], 0, 0, 0);
    }
  }
  __syncthreads();  // all compute done before epilogue reuses Sm

  if (epi == 0) {
    if (bn >= 2048) {
      // ---- V block: transpose C-tile through LDS, coalesced store ----
#pragma unroll
      for (int mf = 0; mf < 4; ++mf)
#pragma unroll
        for (int r = 0; r < 4; ++r) {
          int srow = wr * 64 + mf * 16 + l4 * 4 + r;
#pragma unroll
          for (int nf = 0; nf < 4; ++nf) {
            int dloc = wc * 64 + nf * 16 + l15;
            Sm[dloc * 132 + srow] = f2bf(acc[mf][nf][r]);
          }
        }
      __syncthreads();
      const int bb = bm >> 11, s0 = bm & 2047;
      const int dbase = bn - 2048;
#pragma unroll
      for (int it = 0; it < 8; ++it) {
        int row = it * 16 + (tid >> 4);   // dloc 0..127
        int scol = (tid & 15) * 8;        // srow chunk
        short8 val = *(const short8*)&Sm[row * 132 + scol];
        int dglob = dbase + row;
        int hh = dglob >> 6, dh = dglob & 63;
        *(short8*)&v[((size_t)(bb * 16 + hh) * 64 + dh) * 2048 + s0 + scol] = val;
      }
    } else {
      // ---- Q/K block: stage [srow][dloc] in LDS, coalesced short8 store ----
      const bool isK = (bn >= 1024);
      const float scl = isK ? KSCL : 1.0f;
#pragma unroll
      for (int mf = 0; mf < 4; ++mf)
#pragma unroll
        for (int r = 0; r < 4; ++r) {
          int srow = wr * 64 + mf * 16 + l4 * 4 + r;
#pragma unroll
          for (int nf = 0; nf < 4; ++nf) {
            int dloc = wc * 64 + nf * 16 + l15;
            Sm[srow * 132 + dloc] = f2bf(acc[mf][nf][r] * scl);
          }
        }
      __syncthreads();
      const int bb = bm >> 11, s0 = bm & 2047;
      short* dst = isK ? k : q;
#pragma unroll
      for (int it = 0; it < 8; ++it) {
        int row = it * 16 + (tid >> 4);   // srow (s offset) 0..127
        int nc8 = (tid & 15) * 8;         // dloc chunk
        short8 val = *(const short8*)&Sm[row * 132 + nc8];
        int n = bn + nc8;                  // bn%64==0 -> dh chunk-aligned
        int h = (n >> 6) & 15, dh = n & 63;
        *(short8*)&dst[((size_t)(bb * 16 + h) * 2048 + s0 + row) * 64 + dh] = val;
      }
    }
  } else {
#pragma unroll
    for (int mf = 0; mf < 4; ++mf)
#pragma unroll
      for (int r = 0; r < 4; ++r) {
        int m = bm + wr * 64 + mf * 16 + l4 * 4 + r;
#pragma unroll
        for (int nf = 0; nf < 4; ++nf) {
          int n = bn + wc * 64 + nf * 16 + l15;
          outF[(size_t)m * N + n] = acc[mf][nf][r];
        }
      }
  }
}

// ---------------- causal flash attention (R24 best: VALU softmax) ---------
// Q,K: [BH=64][S=2048][64] bf16 (K pre-scaled). V: [BH=64][64][S=2048] bf16.
// Out: [B][S][H][64] bf16.
// 84 VGPR / 28% occupancy sweet spot: permlane exchanges, max3 tree,
// cvt_pk pack, defer-max, pure-DMA dbuf staging, 1 barrier/tile.
__global__ __launch_bounds__(256) void attn_fwd(const short* __restrict__ Qb,
                                                const short* __restrict__ Kb,
                                                const short* __restrict__ Vtg,
                                                short* __restrict__ Ob) {
  __shared__ short Kl[2][64 * 64];  // [k][d], FSWZ via pre-swizzled src
  __shared__ short Vt[2][64 * 64];  // [d][k], FSWZ via pre-swizzled src
  const int tid = threadIdx.x, lane = tid & 63, wv = tid >> 6;
  const int l31 = lane & 31, l32 = lane >> 5;
  const int bh = blockIdx.x;
  const int qt = (int)gridDim.y - 1 - (int)blockIdx.y;  // heavy-first
  const int b = bh >> 4, h = bh & 15;
  const size_t base = (size_t)bh * 2048 * 64;   // Q/K base ([s][d])
  const size_t baseV = (size_t)bh * 64 * 2048;  // V^T base ([d][s])
  const int q0 = qt * 128;
  const int qw0 = q0 + wv * 32;
  const int qg = qw0 + l31;

  // Q as B-fragments: qf[dk] covers d = dk*16 + l32*8 + e
  short8 qf[4];
#pragma unroll
  for (int dk = 0; dk < 4; ++dk)
    qf[dk] = *(const short8*)(Qb + base + (size_t)qg * 64 + dk * 16 + l32 * 8);

  f32x16 oacc[2] = {};
  float mrun = -1e30f, lrun = 0.f;

  const int nt = 2 * qt + 2;
  // prologue: issue tile 0 DMAs (K rows = k, V^T rows = d; both swizzled src)
#pragma unroll
  for (int i = 0; i < 2; ++i) {
    int c = i * 256 + tid;
    int row = c >> 3, j = c & 7;
    int js = (j ^ FSWZ(row)) * 8;
    gload_lds16(Kb + base + (size_t)row * 64 + js, (char*)Kl[0] + (size_t)c * 16);
    gload_lds16(Vtg + baseV + (size_t)row * 2048 + js, (char*)Vt[0] + (size_t)c * 16);
  }

  for (int t = 0; t < nt; ++t) {
    const int cur = t & 1;
    const int kv0 = t * 64;
    __syncthreads();  // buf[cur] DMAs drained; buf[cur^1] readers retired

    if (t + 1 < nt) {  // issue next tile's DMAs; fly over compute
      const int kv1 = kv0 + 64;
#pragma unroll
      for (int i = 0; i < 2; ++i) {
        int c = i * 256 + tid;
        int row = c >> 3, j = c & 7;
        int js = (j ^ FSWZ(row)) * 8;
        gload_lds16(Kb + base + (size_t)(kv1 + row) * 64 + js,
                    (char*)Kl[cur ^ 1] + (size_t)c * 16);
        gload_lds16(Vtg + baseV + (size_t)row * 2048 + kv1 + js,
                    (char*)Vt[cur ^ 1] + (size_t)c * 16);
      }
    }

    if (kv0 <= qw0 + 31) {
      // ---- QK^T (swapped): sc[kb] = S^T tile ----
      f32x16 sc[2] = {};
#pragma unroll
      for (int dk = 0; dk < 4; ++dk)
#pragma unroll
        for (int kb = 0; kb < 2; ++kb) {
          int row = kb * 32 + l31;
          short8 kf =
              *(const short8*)&Kl[cur][row * 64 + (((dk * 2 + l32) ^ FSWZ(row)) * 8)];
          sc[kb] = __builtin_amdgcn_mfma_f32_32x32x16_bf16(kf, qf[dk], sc[kb], 0, 0, 0);
        }

      // ---- causal mask: only on frontier tiles (wave-uniform branch) ----
      if (kv0 + 63 > qw0) {
        const int thr2 = qg - kv0 - 4 * l32;
#pragma unroll
        for (int kb = 0; kb < 2; ++kb)
#pragma unroll
          for (int r = 0; r < 16; ++r) {
            if (kb * 32 + ((r & 3) + 8 * (r >> 2)) > thr2) sc[kb][r] = -1e30f;
          }
      }

      // ---- softmax (K pre-scaled; log2 domain); lane owns q-row l31 ----
      float m0 = max3f(sc[0][0], sc[0][1], sc[0][2]);
      float m1 = max3f(sc[0][3], sc[0][4], sc[0][5]);
      float m2 = max3f(sc[0][6], sc[0][7], sc[0][8]);
      float m3 = max3f(sc[0][9], sc[0][10], sc[0][11]);
      float m4 = max3f(sc[0][12], sc[0][13], sc[0][14]);
      float m5 = max3f(sc[0][15], sc[1][0], sc[1][1]);
      float m6 = max3f(sc[1][2], sc[1][3], sc[1][4]);
      float m7 = max3f(sc[1][5], sc[1][6], sc[1][7]);
      float m8 = max3f(sc[1][8], sc[1][9], sc[1][10]);
      float m9 = max3f(sc[1][11], sc[1][12], sc[1][13]);
      float ma = fmaxf(sc[1][14], sc[1][15]);
      float mb = max3f(m0, m1, m2);
      float mc = max3f(m3, m4, m5);
      float md = max3f(m6, m7, m8);
      float me = max3f(m9, ma, mb);
      float mx = max3f(mc, md, me);
      {  // lane^32 exchange via permlane (partner = l32 ? ret.x : ret.y)
        u32x2 mm = __builtin_amdgcn_permlane32_swap(__float_as_uint(mx),
                                                    __float_as_uint(mx), false, false);
        mx = fmaxf(mx, __uint_as_float(l32 ? mm[0] : mm[1]));
      }
      // defer-max: rescale only when max grew past THR (=8*log2e)
      if (!__all(mx - mrun <= 11.5416f)) {
        float mnew = fmaxf(mrun, mx);
        float alpha = exp2f(mrun - mnew);
        lrun *= alpha;
#pragma unroll
        for (int dt = 0; dt < 2; ++dt)
#pragma unroll
          for (int r = 0; r < 16; ++r) oacc[dt][r] *= alpha;
        mrun = mnew;
      }
      float pp[2][16];
#pragma unroll
      for (int kb = 0; kb < 2; ++kb)
#pragma unroll
        for (int r = 0; r < 16; ++r) pp[kb][r] = exp2f(sc[kb][r] - mrun);
      // sum: pairwise tree then lane^32 exchange via permlane
      float s8[8];
#pragma unroll
      for (int i = 0; i < 8; ++i)
        s8[i] = (pp[0][i] + pp[0][i + 8]) + (pp[1][i] + pp[1][i + 8]);
      float ls = ((s8[0] + s8[4]) + (s8[1] + s8[5])) + ((s8[2] + s8[6]) + (s8[3] + s8[7]));
      {
        u32x2 sm = __builtin_amdgcn_permlane32_swap(__float_as_uint(ls),
                                                    __float_as_uint(ls), false, false);
        ls += __uint_as_float(l32 ? sm[0] : sm[1]);
      }
      lrun += ls;

      // ---- pack P pairs: W[kb][g][u] covers k0 = kb*32+8g+4*l32+2u ----
      unsigned int W[2][4][2];
#pragma unroll
      for (int kb = 0; kb < 2; ++kb)
#pragma unroll
        for (int g = 0; g < 4; ++g)
#pragma unroll
          for (int u = 0; u < 2; ++u)
            W[kb][g][u] = cvtpk(pp[kb][g * 4 + 2 * u], pp[kb][g * 4 + 2 * u + 1]);

      // ---- redistribute into PV B-fragments via permlane32_swap ----
      u32x4 pf[4];
#pragma unroll
      for (int kblk = 0; kblk < 4; ++kblk) {
        const int kbh = kblk >> 1;
#pragma unroll
        for (int u = 0; u < 2; ++u) {
          u32x2 rr = __builtin_amdgcn_permlane32_swap(
              W[kbh][2 * (kblk & 1)][u], W[kbh][2 * (kblk & 1) + 1][u], false, false);
          pf[kblk][0 + u] = rr[0];
          pf[kblk][2 + u] = rr[1];
        }
      }

      // ---- PV (swapped): oacc[dt] += V^T[dt] x P^T ----
#pragma unroll
      for (int dt = 0; dt < 2; ++dt)
#pragma unroll
        for (int kblk = 0; kblk < 4; ++kblk) {
          int row = dt * 32 + l31;
          short8 vf =
              *(const short8*)&Vt[cur][row * 64 + (((kblk * 2 + l32) ^ FSWZ(row)) * 8)];
          oacc[dt] = __builtin_amdgcn_mfma_f32_32x32x16_bf16(
              vf, __builtin_bit_cast(short8, pf[kblk]), oacc[dt], 0, 0, 0);
        }
    }
  }

  // ---- epilogue: pack adjacent-d pairs into dword stores ----
  float inv = 1.f / lrun;
#pragma unroll
  for (int dt = 0; dt < 2; ++dt)
#pragma unroll
    for (int r = 0; r < 16; r += 2) {
      int d = dt * 32 + (r & 3) + 8 * (r >> 2) + 4 * l32;  // r even -> d even
      unsigned int pk = cvtpk(oacc[dt][r] * inv, oacc[dt][r + 1] * inv);
      *(unsigned int*)&Ob[(size_t)(b * 2048 + qg) * 1024 + h * 64 + d] = pk;
    }
}

// ---------------- launch ----------------
extern "C" void kernel_launch(void* const* d_in, const int* in_sizes, int n_in,
                              void* d_out, int out_size, void* d_ws, size_t ws_size,
                              hipStream_t stream) {
  const float* x = (const float*)d_in[0];      // [4,2048,1024]
  const float* w_qkv = (const float*)d_in[1];  // [3072,1024]
  const float* w_out = (const float*)d_in[2];  // [1024,1024]
  float* out = (float*)d_out;                  // [4,2048,1024] fp32

  char* ws = (char*)d_ws;
  const size_t MB = 1024 * 1024;
  short* xb    = (short*)(ws + 0 * MB);    // 16 MB; dead after QKV GEMM
  short* wqkvb = (short*)(ws + 16 * MB);   // 6 MB
  short* woutb = (short*)(ws + 22 * MB);   // 2 MB
  short* qb    = (short*)(ws + 24 * MB);   // 16 MB  [64][2048][64]
  short* kb    = (short*)(ws + 40 * MB);   // 16 MB (pre-scaled by KSCL)
  short* vb    = (short*)(ws + 56 * MB);   // 16 MB  [64][64][2048] (V^T)
  short* ao    = xb;                       // reuse xb for attn output

  cvt_all<<<6144, 256, 0, stream>>>(x, w_qkv, w_out, xb, wqkvb, woutb);

  gemm_bt<<<dim3(3072 / 128, 8192 / 128), 256, 0, stream>>>(
      xb, wqkvb, 1024, 0, qb, kb, vb, nullptr, 3072);

  attn_fwd<<<dim3(64, 16), 256, 0, stream>>>(qb, kb, vb, ao);

  gemm_bt<<<dim3(1024 / 128, 8192 / 128), 256, 0, stream>>>(
      ao, woutb, 1024, 1, nullptr, nullptr, nullptr, out, 1024);
}